// Round 2
// baseline (549.304 us; speedup 1.0000x reference)
//
#include <hip/hip_runtime.h>
#include <stdint.h>
#include <stddef.h>

#define T_SEQ 2048
#define NH    12
#define DH    64
#define NB    2
#define NEMB  768

using f32x4  = __attribute__((ext_vector_type(4))) float;
using bf16x8 = __attribute__((ext_vector_type(8))) short;

#define MFMA(a, b, c) __builtin_amdgcn_mfma_f32_16x16x32_bf16((a), (b), (c), 0, 0, 0)

__device__ __forceinline__ short f2bf(float f) {
    union { float f; uint32_t u; } v; v.f = f;
    uint32_t u = v.u + 0x7FFFu + ((v.u >> 16) & 1u);
    return (short)(u >> 16);
}

// ---------------------------------------------------------------------------
// Kernel 1: fp32 -> bf16 conversion of x, w_q, w_k, w_v, w_o
// ---------------------------------------------------------------------------
__global__ void cvt_kernel(const float* __restrict__ x,  const float* __restrict__ wq,
                           const float* __restrict__ wk, const float* __restrict__ wv,
                           const float* __restrict__ wo,
                           short* __restrict__ xb,  short* __restrict__ wqb,
                           short* __restrict__ wkb, short* __restrict__ wvb,
                           short* __restrict__ wob) {
    const float* src; short* dst; int n;
    switch (blockIdx.y) {
        case 0:  src = x;  dst = xb;  n = NB * T_SEQ * NEMB; break;
        case 1:  src = wq; dst = wqb; n = NEMB * NEMB; break;
        case 2:  src = wk; dst = wkb; n = NEMB * NEMB; break;
        case 3:  src = wv; dst = wvb; n = NEMB * NEMB; break;
        default: src = wo; dst = wob; n = NEMB * NEMB; break;
    }
    int n4 = n >> 2;
    for (int i = blockIdx.x * blockDim.x + threadIdx.x; i < n4; i += gridDim.x * blockDim.x) {
        float4 v = ((const float4*)src)[i];
        short4 o;
        o.x = f2bf(v.x); o.y = f2bf(v.y); o.z = f2bf(v.z); o.w = f2bf(v.w);
        ((short4*)dst)[i] = o;
    }
}

// ---------------------------------------------------------------------------
// Kernel 2: QKV projection GEMM.  C[t,d] = sum_c xb[t,c] * W[d,c]
// 128x128 tile, BK=64, 4 waves (2x2), swizzled LDS, bf16 MFMA 16x16x32.
// mode (blockIdx.z): 0 -> Q head-major, 1 -> K head-major, 2 -> V transposed.
// ---------------------------------------------------------------------------
__global__ __launch_bounds__(256, 2) void qkv_gemm(
        const short* __restrict__ xb,  const short* __restrict__ wqb,
        const short* __restrict__ wkb, const short* __restrict__ wvb,
        short* __restrict__ Qh, short* __restrict__ Kh, short* __restrict__ Vt) {
    __shared__ short As[128 * 64];
    __shared__ short Bs[128 * 64];
    const int mode = blockIdx.z;
    const short* Wm = (mode == 0) ? wqb : (mode == 1) ? wkb : wvb;
    const int rowbase = blockIdx.x * 128;
    const int colbase = blockIdx.y * 128;
    const int tid = threadIdx.x;
    const int lane = tid & 63;
    const int wid = tid >> 6;
    const int wm = wid >> 1, wn = wid & 1;
    const int g = lane >> 4, c = lane & 15;

    const f32x4 z4 = {0.f, 0.f, 0.f, 0.f};
    f32x4 acc[4][4];
#pragma unroll
    for (int i = 0; i < 4; ++i)
#pragma unroll
        for (int j = 0; j < 4; ++j) acc[i][j] = z4;

    for (int kt = 0; kt < 12; ++kt) {
        __syncthreads();
#pragma unroll
        for (int p = 0; p < 4; ++p) {
            int lin = p * 256 + tid;
            int row = lin >> 3, kb = lin & 7;
            int sw = ((kb * 16) ^ ((row & 7) << 4)) >> 1;
            *(bf16x8*)&As[row * 64 + sw] = *(const bf16x8*)&xb[(rowbase + row) * NEMB + kt * 64 + kb * 8];
            *(bf16x8*)&Bs[row * 64 + sw] = *(const bf16x8*)&Wm[(colbase + row) * NEMB + kt * 64 + kb * 8];
        }
        __syncthreads();
#pragma unroll
        for (int ks = 0; ks < 2; ++ks) {
            bf16x8 a[4], b[4];
#pragma unroll
            for (int mi = 0; mi < 4; ++mi) {
                int row = wm * 64 + mi * 16 + c;
                int kb = ((ks * 64 + g * 16) ^ ((row & 7) << 4)) >> 1;
                a[mi] = *(const bf16x8*)&As[row * 64 + kb];
            }
#pragma unroll
            for (int ni = 0; ni < 4; ++ni) {
                int row = wn * 64 + ni * 16 + c;
                int kb = ((ks * 64 + g * 16) ^ ((row & 7) << 4)) >> 1;
                b[ni] = *(const bf16x8*)&Bs[row * 64 + kb];
            }
#pragma unroll
            for (int mi = 0; mi < 4; ++mi)
#pragma unroll
                for (int ni = 0; ni < 4; ++ni)
                    acc[mi][ni] = MFMA(a[mi], b[ni], acc[mi][ni]);
        }
    }
    // epilogue: D layout row = g*4 + r, col = c (within each 16x16)
#pragma unroll
    for (int mi = 0; mi < 4; ++mi) {
        int trow0 = rowbase + wm * 64 + mi * 16 + g * 4;
#pragma unroll
        for (int ni = 0; ni < 4; ++ni) {
            int col = colbase + wn * 64 + ni * 16 + c;
            int h = col >> 6, dh = col & 63;
#pragma unroll
            for (int r = 0; r < 4; ++r) {
                int trow = trow0 + r;
                int bb = trow >> 11, t = trow & 2047;
                int bh = bb * NH + h;
                short val = f2bf(acc[mi][ni][r]);
                if (mode == 2)      Vt[(size_t)bh * (DH * T_SEQ) + dh * T_SEQ + t] = val;
                else if (mode == 0) Qh[((size_t)bh * T_SEQ + t) * DH + dh] = val;
                else                Kh[((size_t)bh * T_SEQ + t) * DH + dh] = val;
            }
        }
    }
}

// ---------------------------------------------------------------------------
// Kernel 3: fused causal attention.  Per (bh, 128-row Q tile):
//   pass 1: exact softmax denominators (exp without max-subtract; logits bounded)
//   pass 2: recompute S, write normalized weights fp32, P->LDS->PV accumulate
//   then zero-fill upper triangle, write O (bf16) for the output projection.
// ---------------------------------------------------------------------------
__global__ __launch_bounds__(256, 2) void attn_kernel(
        const short* __restrict__ Qh, const short* __restrict__ Kh,
        const short* __restrict__ Vt, float* __restrict__ Wout,
        short* __restrict__ Ob) {
    __shared__ short Ks[64 * 64];
    __shared__ short Vs[64 * 64];
    __shared__ short Ps[4][32 * 64];

    const int bh = blockIdx.y;
    const int bb = bh / NH, h = bh % NH;
    const int qtile = blockIdx.x;
    const int qbase = qtile * 128;
    const int tid = threadIdx.x, lane = tid & 63, w = tid >> 6;
    const int g = lane >> 4, c = lane & 15;
    const int nkt = 2 * (qtile + 1);
    const int stripmax = qbase + w * 32 + 31;

    const short* Qp = Qh + (size_t)bh * T_SEQ * DH;
    const short* Kp = Kh + (size_t)bh * T_SEQ * DH;
    const short* Vp = Vt + (size_t)bh * DH * T_SEQ;
    float* Wp = Wout + (size_t)bh * T_SEQ * T_SEQ;

    const f32x4 z4 = {0.f, 0.f, 0.f, 0.f};

    // Q fragments for this wave's 32-row strip (A-frag: row = c, k = g*8+i)
    bf16x8 q[2][2];
#pragma unroll
    for (int mi = 0; mi < 2; ++mi)
#pragma unroll
        for (int ks = 0; ks < 2; ++ks)
            q[mi][ks] = *(const bf16x8*)&Qp[(qbase + w * 32 + mi * 16 + c) * DH + ks * 32 + g * 8];

    // ---- pass 1: denominators ----
    float lsum[2][4];
#pragma unroll
    for (int mi = 0; mi < 2; ++mi)
#pragma unroll
        for (int r = 0; r < 4; ++r) lsum[mi][r] = 0.f;

    for (int kt = 0; kt < nkt; ++kt) {
        __syncthreads();
#pragma unroll
        for (int p = 0; p < 2; ++p) {
            int lin = p * 256 + tid;
            int row = lin >> 3, kb = lin & 7;
            int sw = ((kb * 16) ^ ((row & 7) << 4)) >> 1;
            *(bf16x8*)&Ks[row * 64 + sw] = *(const bf16x8*)&Kp[(kt * 64 + row) * DH + kb * 8];
        }
        __syncthreads();
        if (kt * 64 > stripmax) continue;  // fully masked for this wave
#pragma unroll
        for (int ni = 0; ni < 4; ++ni) {
            f32x4 s[2] = {z4, z4};
#pragma unroll
            for (int ks = 0; ks < 2; ++ks) {
                int krow = ni * 16 + c;
                int kb = ((ks * 64 + g * 16) ^ ((krow & 7) << 4)) >> 1;
                bf16x8 kf = *(const bf16x8*)&Ks[krow * 64 + kb];
                s[0] = MFMA(q[0][ks], kf, s[0]);
                s[1] = MFMA(q[1][ks], kf, s[1]);
            }
            int colg = kt * 64 + ni * 16 + c;
#pragma unroll
            for (int mi = 0; mi < 2; ++mi) {
                int row0 = qbase + w * 32 + mi * 16 + g * 4;
#pragma unroll
                for (int r = 0; r < 4; ++r) {
                    float e = __expf(s[mi][r] * 0.125f);
                    lsum[mi][r] += (colg <= row0 + r) ? e : 0.f;
                }
            }
        }
    }
    float rl[2][4];
#pragma unroll
    for (int mi = 0; mi < 2; ++mi)
#pragma unroll
        for (int r = 0; r < 4; ++r) {
            float v = lsum[mi][r];
            v += __shfl_xor(v, 1); v += __shfl_xor(v, 2);
            v += __shfl_xor(v, 4); v += __shfl_xor(v, 8);
            rl[mi][r] = 1.0f / v;
        }

    // ---- pass 2: weights write + PV ----
    f32x4 o[2][4];
#pragma unroll
    for (int mi = 0; mi < 2; ++mi)
#pragma unroll
        for (int di = 0; di < 4; ++di) o[mi][di] = z4;

    for (int kt = 0; kt < nkt; ++kt) {
        __syncthreads();
#pragma unroll
        for (int p = 0; p < 2; ++p) {
            int lin = p * 256 + tid;
            int row = lin >> 3, kb = lin & 7;
            int sw = ((kb * 16) ^ ((row & 7) << 4)) >> 1;
            *(bf16x8*)&Ks[row * 64 + sw] = *(const bf16x8*)&Kp[(kt * 64 + row) * DH + kb * 8];
            *(bf16x8*)&Vs[row * 64 + sw] = *(const bf16x8*)&Vp[row * T_SEQ + kt * 64 + kb * 8];
        }
        __syncthreads();
        if (kt * 64 > stripmax) {
            // fully masked: just store zeros for this wave's 32x64 region
            float4 z = make_float4(0.f, 0.f, 0.f, 0.f);
#pragma unroll
            for (int i = 0; i < 8; ++i) {
                int rowg = qbase + w * 32 + i * 4 + g;
                *(float4*)&Wp[(size_t)rowg * T_SEQ + kt * 64 + c * 4] = z;
            }
            continue;
        }
#pragma unroll
        for (int ni = 0; ni < 4; ++ni) {
            f32x4 s[2] = {z4, z4};
#pragma unroll
            for (int ks = 0; ks < 2; ++ks) {
                int krow = ni * 16 + c;
                int kb = ((ks * 64 + g * 16) ^ ((krow & 7) << 4)) >> 1;
                bf16x8 kf = *(const bf16x8*)&Ks[krow * 64 + kb];
                s[0] = MFMA(q[0][ks], kf, s[0]);
                s[1] = MFMA(q[1][ks], kf, s[1]);
            }
            int colg = kt * 64 + ni * 16 + c;
#pragma unroll
            for (int mi = 0; mi < 2; ++mi) {
                int rowl = w * 32 + mi * 16 + g * 4;
                float* wptr = Wp + (size_t)(qbase + rowl) * T_SEQ + colg;
#pragma unroll
                for (int r = 0; r < 4; ++r) {
                    float e = __expf(s[mi][r] * 0.125f);
                    float wgt = (colg <= qbase + rowl + r) ? e * rl[mi][r] : 0.f;
                    wptr[(size_t)r * T_SEQ] = wgt;
                    int prow = mi * 16 + g * 4 + r;
                    int pidx = prow * 64 + ((((ni * 16 + c) * 2) ^ ((prow & 7) << 4)) >> 1);
                    Ps[w][pidx] = f2bf(wgt);
                }
            }
        }
        // PV: O += P @ V  (P as A-frag from LDS, V^T as B-frag)
#pragma unroll
        for (int ks = 0; ks < 2; ++ks) {
            bf16x8 pa[2];
#pragma unroll
            for (int mi = 0; mi < 2; ++mi) {
                int prow = mi * 16 + c;
                int kb = ((ks * 64 + g * 16) ^ ((prow & 7) << 4)) >> 1;
                pa[mi] = *(const bf16x8*)&Ps[w][prow * 64 + kb];
            }
#pragma unroll
            for (int di = 0; di < 4; ++di) {
                int vrow = di * 16 + c;
                int kb = ((ks * 64 + g * 16) ^ ((vrow & 7) << 4)) >> 1;
                bf16x8 vf = *(const bf16x8*)&Vs[vrow * 64 + kb];
                o[0][di] = MFMA(pa[0], vf, o[0][di]);
                o[1][di] = MFMA(pa[1], vf, o[1][di]);
            }
        }
    }

    // zero-fill strictly-upper region beyond the block's tiles
    int c0 = nkt * 64;
    if (c0 < T_SEQ) {
        float4 z = make_float4(0.f, 0.f, 0.f, 0.f);
        for (int r = 0; r < 128; ++r) {
            size_t base = (size_t)(qbase + r) * T_SEQ;
            for (int cc = c0 + tid * 4; cc < T_SEQ; cc += 1024)
                *(float4*)&Wp[base + cc] = z;
        }
    }

    // write O (bf16) into [4096][768] for the output projection
#pragma unroll
    for (int mi = 0; mi < 2; ++mi)
#pragma unroll
        for (int di = 0; di < 4; ++di)
#pragma unroll
            for (int r = 0; r < 4; ++r) {
                int rowg = qbase + w * 32 + mi * 16 + g * 4 + r;
                Ob[(size_t)(bb * T_SEQ + rowg) * NEMB + h * 64 + di * 16 + c] = f2bf(o[mi][di][r]);
            }
}

// ---------------------------------------------------------------------------
// Kernel 4: output projection.  final[t,d] = sum_c Ob[t,c] * wo[d,c]  (fp32 out)
// ---------------------------------------------------------------------------
__global__ __launch_bounds__(256, 2) void out_gemm(
        const short* __restrict__ Ob, const short* __restrict__ wob,
        float* __restrict__ outp) {
    __shared__ short As[128 * 64];
    __shared__ short Bs[128 * 64];
    const int rowbase = blockIdx.x * 128;
    const int colbase = blockIdx.y * 128;
    const int tid = threadIdx.x;
    const int lane = tid & 63;
    const int wid = tid >> 6;
    const int wm = wid >> 1, wn = wid & 1;
    const int g = lane >> 4, c = lane & 15;

    const f32x4 z4 = {0.f, 0.f, 0.f, 0.f};
    f32x4 acc[4][4];
#pragma unroll
    for (int i = 0; i < 4; ++i)
#pragma unroll
        for (int j = 0; j < 4; ++j) acc[i][j] = z4;

    for (int kt = 0; kt < 12; ++kt) {
        __syncthreads();
#pragma unroll
        for (int p = 0; p < 4; ++p) {
            int lin = p * 256 + tid;
            int row = lin >> 3, kb = lin & 7;
            int sw = ((kb * 16) ^ ((row & 7) << 4)) >> 1;
            *(bf16x8*)&As[row * 64 + sw] = *(const bf16x8*)&Ob[(rowbase + row) * NEMB + kt * 64 + kb * 8];
            *(bf16x8*)&Bs[row * 64 + sw] = *(const bf16x8*)&wob[(colbase + row) * NEMB + kt * 64 + kb * 8];
        }
        __syncthreads();
#pragma unroll
        for (int ks = 0; ks < 2; ++ks) {
            bf16x8 a[4], b[4];
#pragma unroll
            for (int mi = 0; mi < 4; ++mi) {
                int row = wm * 64 + mi * 16 + c;
                int kb = ((ks * 64 + g * 16) ^ ((row & 7) << 4)) >> 1;
                a[mi] = *(const bf16x8*)&As[row * 64 + kb];
            }
#pragma unroll
            for (int ni = 0; ni < 4; ++ni) {
                int row = wn * 64 + ni * 16 + c;
                int kb = ((ks * 64 + g * 16) ^ ((row & 7) << 4)) >> 1;
                b[ni] = *(const bf16x8*)&Bs[row * 64 + kb];
            }
#pragma unroll
            for (int mi = 0; mi < 4; ++mi)
#pragma unroll
                for (int ni = 0; ni < 4; ++ni)
                    acc[mi][ni] = MFMA(a[mi], b[ni], acc[mi][ni]);
        }
    }
#pragma unroll
    for (int mi = 0; mi < 4; ++mi) {
        int trow0 = rowbase + wm * 64 + mi * 16 + g * 4;
#pragma unroll
        for (int ni = 0; ni < 4; ++ni) {
            int col = colbase + wn * 64 + ni * 16 + c;
#pragma unroll
            for (int r = 0; r < 4; ++r)
                outp[(size_t)(trow0 + r) * NEMB + col] = acc[mi][ni][r];
        }
    }
}

// ---------------------------------------------------------------------------
extern "C" void kernel_launch(void* const* d_in, const int* in_sizes, int n_in,
                              void* d_out, int out_size, void* d_ws, size_t ws_size,
                              hipStream_t stream) {
    (void)in_sizes; (void)n_in; (void)out_size; (void)ws_size;
    const float* x  = (const float*)d_in[0];
    const float* wq = (const float*)d_in[1];
    const float* wk = (const float*)d_in[2];
    const float* wv = (const float*)d_in[3];
    const float* wo = (const float*)d_in[4];
    float* outp = (float*)d_out;                     // final [4096][768]
    float* wout = outp + (size_t)NB * T_SEQ * NEMB;  // weights [24][2048][2048]

    char* ws = (char*)d_ws;
    size_t off = 0;
    short* xb  = (short*)(ws + off); off += (size_t)NB * T_SEQ * NEMB * 2;
    short* wqb = (short*)(ws + off); off += (size_t)NEMB * NEMB * 2;
    short* wkb = (short*)(ws + off); off += (size_t)NEMB * NEMB * 2;
    short* wvb = (short*)(ws + off); off += (size_t)NEMB * NEMB * 2;
    short* wob = (short*)(ws + off); off += (size_t)NEMB * NEMB * 2;
    short* Qh  = (short*)(ws + off); off += (size_t)NB * NH * T_SEQ * DH * 2;
    short* Kh  = (short*)(ws + off); off += (size_t)NB * NH * T_SEQ * DH * 2;
    short* Vt  = (short*)(ws + off); off += (size_t)NB * NH * T_SEQ * DH * 2;
    short* Ob  = (short*)(ws + off); off += (size_t)NB * T_SEQ * NEMB * 2;

    cvt_kernel<<<dim3(512, 5), 256, 0, stream>>>(x, wq, wk, wv, wo, xb, wqb, wkb, wvb, wob);
    qkv_gemm<<<dim3(32, 6, 3), 256, 0, stream>>>(xb, wqb, wkb, wvb, Qh, Kh, Vt);
    attn_kernel<<<dim3(16, NB * NH), 256, 0, stream>>>(Qh, Kh, Vt, wout, Ob);
    out_gemm<<<dim3(32, 6), 256, 0, stream>>>(Ob, wob, outp);
}